// Round 1
// baseline (30.388 us; speedup 1.0000x reference)
//
#include <hip/hip_runtime.h>
#include <math.h>

// Problem constants (match reference)
#define VOCAB   100000
#define EMBED_D 128
#define BATCH_N 16384
#define CTX     8
#define NNEG    5

#define NBLOCKS 1024
#define TPB     256   // 4 waves per block
#define WAVES_PER_BLOCK (TPB / 64)
#define NWAVES  (NBLOCKS * WAVES_PER_BLOCK)

// Stage 1: per-block partial sums of the 6 scalar contractions.
// One wave handles one batch element at a time; lane i owns dims [2i, 2i+1].
__global__ __launch_bounds__(TPB) void cbow_partial_kernel(
    const int* __restrict__ pos_u,   // [B, C]
    const int* __restrict__ pos_w,   // [B]
    const int* __restrict__ neg_w,   // [B, NEG]
    const float* __restrict__ W,     // [VOCAB, D]
    float* __restrict__ partials)    // [NBLOCKS, 6]
{
    const int lane = threadIdx.x & 63;
    const int wib  = threadIdx.x >> 6;                 // wave-in-block
    const int gwave = blockIdx.x * WAVES_PER_BLOCK + wib;

    const float2* __restrict__ W2 = (const float2*)W;  // row stride = 64 float2

    float acc_p  = 0.f;
    float acc_n0 = 0.f, acc_n1 = 0.f, acc_n2 = 0.f, acc_n3 = 0.f, acc_n4 = 0.f;

    for (int b = gwave; b < BATCH_N; b += NWAVES) {
        const int bu = __builtin_amdgcn_readfirstlane(b);  // wave-uniform -> s_loads

        // Usum[b, 2*lane .. 2*lane+1] = sum_c W[pos_u[b,c]]
        float2 us = make_float2(0.f, 0.f);
        #pragma unroll
        for (int c = 0; c < CTX; ++c) {
            const int idx = pos_u[bu * CTX + c];
            const float2 v = W2[(size_t)idx * (EMBED_D / 2) + lane];
            us.x += v.x; us.y += v.y;
        }

        // positive score partial
        {
            const int ip = pos_w[bu];
            const float2 wp = W2[(size_t)ip * (EMBED_D / 2) + lane];
            acc_p += us.x * wp.x + us.y * wp.y;
        }

        // 5 negative score partials
        {
            const int i0 = neg_w[bu * NNEG + 0];
            const int i1 = neg_w[bu * NNEG + 1];
            const int i2 = neg_w[bu * NNEG + 2];
            const int i3 = neg_w[bu * NNEG + 3];
            const int i4 = neg_w[bu * NNEG + 4];
            const float2 w0 = W2[(size_t)i0 * (EMBED_D / 2) + lane];
            const float2 w1 = W2[(size_t)i1 * (EMBED_D / 2) + lane];
            const float2 w2 = W2[(size_t)i2 * (EMBED_D / 2) + lane];
            const float2 w3 = W2[(size_t)i3 * (EMBED_D / 2) + lane];
            const float2 w4 = W2[(size_t)i4 * (EMBED_D / 2) + lane];
            acc_n0 += us.x * w0.x + us.y * w0.y;
            acc_n1 += us.x * w1.x + us.y * w1.y;
            acc_n2 += us.x * w2.x + us.y * w2.y;
            acc_n3 += us.x * w3.x + us.y * w3.y;
            acc_n4 += us.x * w4.x + us.y * w4.y;
        }
    }

    // wave reduction of the 6 accumulators
    float vals[6] = {acc_p, acc_n0, acc_n1, acc_n2, acc_n3, acc_n4};
    #pragma unroll
    for (int k = 0; k < 6; ++k) {
        float v = vals[k];
        #pragma unroll
        for (int off = 32; off > 0; off >>= 1)
            v += __shfl_down(v, off, 64);
        vals[k] = v;
    }

    __shared__ float sred[WAVES_PER_BLOCK][6];
    if (lane == 0) {
        #pragma unroll
        for (int k = 0; k < 6; ++k) sred[wib][k] = vals[k];
    }
    __syncthreads();

    if (threadIdx.x < 6) {
        float s = 0.f;
        #pragma unroll
        for (int w = 0; w < WAVES_PER_BLOCK; ++w) s += sred[w][threadIdx.x];
        partials[blockIdx.x * 6 + threadIdx.x] = s;
    }
}

// Stage 2: reduce partials, apply stable log-sigmoid epilogue, write scalar loss.
__global__ void cbow_final_kernel(const float* __restrict__ partials,
                                  float* __restrict__ out)
{
    const int lane = threadIdx.x;  // 64 threads, 1 block
    float s[6] = {0.f, 0.f, 0.f, 0.f, 0.f, 0.f};
    for (int i = lane; i < NBLOCKS; i += 64) {
        #pragma unroll
        for (int k = 0; k < 6; ++k) s[k] += partials[i * 6 + k];
    }
    #pragma unroll
    for (int k = 0; k < 6; ++k) {
        #pragma unroll
        for (int off = 32; off > 0; off >>= 1)
            s[k] += __shfl_down(s[k], off, 64);
    }
    if (lane == 0) {
        // log_sigmoid(x) = min(x,0) - log1p(exp(-|x|))
        const float spos = s[0];
        float loss = -(fminf(spos, 0.f) - log1pf(expf(-fabsf(spos))));
        #pragma unroll
        for (int k = 1; k < 6; ++k) {
            const float x = -s[k];   // log_sigmoid(-s_neg)
            loss -= (fminf(x, 0.f) - log1pf(expf(-fabsf(x))));
        }
        out[0] = loss;
    }
}

extern "C" void kernel_launch(void* const* d_in, const int* in_sizes, int n_in,
                              void* d_out, int out_size, void* d_ws, size_t ws_size,
                              hipStream_t stream) {
    const int*   pos_u = (const int*)d_in[0];
    const int*   pos_w = (const int*)d_in[1];
    const int*   neg_w = (const int*)d_in[2];
    const float* W     = (const float*)d_in[3];
    float* out = (float*)d_out;
    float* partials = (float*)d_ws;   // NBLOCKS*6 floats = 24 KB

    cbow_partial_kernel<<<NBLOCKS, TPB, 0, stream>>>(pos_u, pos_w, neg_w, W, partials);
    cbow_final_kernel<<<1, 64, 0, stream>>>(partials, out);
}